// Round 1
// baseline (78.081 us; speedup 1.0000x reference)
//
#include <hip/hip_runtime.h>

#define BATCH 4
#define NPTS 8192
#define TPB 256
#define RROWS 4
#define ROWS_PER_BLOCK (TPB * RROWS)        // 1024
#define NSLICES 8
#define SLICE (NPTS / NSLICES)              // 1024
#define TOTAL_ROWS (2 * BATCH * NPTS)       // 65536

// Kernel 1: for every row (a-point, both directions), min squared distance
// over one slice of b-points; merge across slices with bitwise atomicMin.
__global__ __launch_bounds__(TPB) void chamfer_min_kernel(
    const float* __restrict__ tpl, const float* __restrict__ src,
    unsigned int* __restrict__ mind2_bits)
{
    __shared__ float sb[SLICE * 3];

    const int rb   = blockIdx.x;       // 0..63  (row-block)
    const int s    = blockIdx.y;       // 0..7   (b slice)
    const int dir  = rb >> 5;          // 0: tpl->src, 1: src->tpl
    const int batch = (rb >> 3) & 3;
    const int tile  = rb & 7;

    const float* pa = dir ? src : tpl;
    const float* pb = dir ? tpl : src;
    const float* paBase = pa + (size_t)batch * NPTS * 3;
    const float* pbBase = pb + (size_t)batch * NPTS * 3 + (size_t)s * SLICE * 3;

    const int t = threadIdx.x;

    // Stage b-slice into LDS (coalesced).
    for (int i = t; i < SLICE * 3; i += TPB) sb[i] = pbBase[i];
    __syncthreads();

    float ax[RROWS], ay[RROWS], az[RROWS], mind2[RROWS];
    const int n0 = tile * ROWS_PER_BLOCK;
#pragma unroll
    for (int k = 0; k < RROWS; ++k) {
        const int row = n0 + k * TPB + t;
        ax[k] = paBase[row * 3 + 0];
        ay[k] = paBase[row * 3 + 1];
        az[k] = paBase[row * 3 + 2];
        mind2[k] = 3.0e38f;
    }

#pragma unroll 4
    for (int m = 0; m < SLICE; ++m) {
        const float bx = sb[m * 3 + 0];
        const float by = sb[m * 3 + 1];
        const float bz = sb[m * 3 + 2];
#pragma unroll
        for (int k = 0; k < RROWS; ++k) {
            const float dx = ax[k] - bx;
            const float dy = ay[k] - by;
            const float dz = az[k] - bz;
            float d2 = dx * dx;
            d2 = fmaf(dy, dy, d2);
            d2 = fmaf(dz, dz, d2);
            mind2[k] = fminf(mind2[k], d2);
        }
    }

    const unsigned int rowBase = (unsigned)dir * (BATCH * NPTS) + (unsigned)batch * NPTS;
#pragma unroll
    for (int k = 0; k < RROWS; ++k) {
        const int row = n0 + k * TPB + t;
        atomicMin(&mind2_bits[rowBase + row], __float_as_uint(mind2[k]));
    }
}

// Kernel 2: sqrt(max(min_d2, 1e-12)) and per-block sums (deterministic tree).
__global__ __launch_bounds__(256) void reduce_rows_kernel(
    const unsigned int* __restrict__ mind2_bits, float* __restrict__ blockSums)
{
    const int gid = blockIdx.x * 256 + threadIdx.x;
    float v = __uint_as_float(mind2_bits[gid]);
    float d = sqrtf(fmaxf(v, 1e-12f));
#pragma unroll
    for (int off = 32; off; off >>= 1) d += __shfl_down(d, off);
    __shared__ float wsum[4];
    const int wave = threadIdx.x >> 6, lane = threadIdx.x & 63;
    if (lane == 0) wsum[wave] = d;
    __syncthreads();
    if (threadIdx.x == 0)
        blockSums[blockIdx.x] = (wsum[0] + wsum[1]) + (wsum[2] + wsum[3]);
}

// Kernel 3: final deterministic sum of 256 block sums -> mean.
__global__ __launch_bounds__(256) void final_kernel(
    const float* __restrict__ blockSums, float* __restrict__ out)
{
    float d = blockSums[threadIdx.x];
#pragma unroll
    for (int off = 32; off; off >>= 1) d += __shfl_down(d, off);
    __shared__ float wsum[4];
    const int wave = threadIdx.x >> 6, lane = threadIdx.x & 63;
    if (lane == 0) wsum[wave] = d;
    __syncthreads();
    if (threadIdx.x == 0) {
        const float total = (wsum[0] + wsum[1]) + (wsum[2] + wsum[3]);
        out[0] = total / (float)(BATCH * NPTS);  // both directions share /32768
    }
}

extern "C" void kernel_launch(void* const* d_in, const int* in_sizes, int n_in,
                              void* d_out, int out_size, void* d_ws, size_t ws_size,
                              hipStream_t stream) {
    const float* tpl = (const float*)d_in[0];
    const float* src = (const float*)d_in[1];
    float* out = (float*)d_out;

    unsigned int* mind2_bits = (unsigned int*)d_ws;
    float* blockSums = (float*)d_ws + TOTAL_ROWS;

    // Init min buffer to ~3.4e38 (bytes 0x7F). Graph-capture safe.
    hipMemsetAsync(d_ws, 0x7F, (size_t)TOTAL_ROWS * sizeof(unsigned int), stream);

    dim3 grid1(TOTAL_ROWS / ROWS_PER_BLOCK, NSLICES);   // (64, 8)
    chamfer_min_kernel<<<grid1, TPB, 0, stream>>>(tpl, src, mind2_bits);

    reduce_rows_kernel<<<TOTAL_ROWS / 256, 256, 0, stream>>>(mind2_bits, blockSums);
    final_kernel<<<1, 256, 0, stream>>>(blockSums, out);
}

// Round 2
// 53.885 us; speedup vs baseline: 1.4490x; 1.4490x over previous
//
#include <hip/hip_runtime.h>

#define BATCH 4
#define NPTS 8192
#define TPB 256
#define RROWS 4
#define ROWS_PER_BLOCK (TPB * RROWS)        // 1024
#define NSLICES 16
#define SLICE (NPTS / NSLICES)              // 512
#define TOTAL_ROWS (2 * BATCH * NPTS)       // 65536

// Monotone float<->uint key: unsigned ascending order == float ascending order.
__device__ __forceinline__ unsigned fkey(float f) {
    unsigned u = __float_as_uint(f);
    return (u & 0x80000000u) ? ~u : (u | 0x80000000u);
}
__device__ __forceinline__ float funkey(unsigned k) {
    return (k & 0x80000000u) ? __uint_as_float(k ^ 0x80000000u) : __uint_as_float(~k);
}

// Kernel 1: per row (a-point, both directions), min of (b^2 - 2 a.b) over one
// slice of b-points; a^2 added per-row, merged across slices via keyed atomicMin.
__global__ __launch_bounds__(TPB) void chamfer_min_kernel(
    const float* __restrict__ tpl, const float* __restrict__ src,
    unsigned int* __restrict__ minkey)
{
    __shared__ float4 sb[SLICE];

    const int rb    = blockIdx.x;      // 0..63  (row-block)
    const int s     = blockIdx.y;      // 0..15  (b slice)
    const int dir   = rb >> 5;         // 0: tpl->src, 1: src->tpl
    const int batch = (rb >> 3) & 3;
    const int tile  = rb & 7;

    const float* pa = dir ? src : tpl;
    const float* pb = dir ? tpl : src;
    const float* paBase = pa + (size_t)batch * NPTS * 3;
    const float* pbBase = pb + (size_t)batch * NPTS * 3 + (size_t)s * SLICE * 3;

    const int t = threadIdx.x;

    // Stage b-slice into LDS as (bx,by,bz,b2) float4.
    for (int i = t; i < SLICE; i += TPB) {
        const float bx = pbBase[i * 3 + 0];
        const float by = pbBase[i * 3 + 1];
        const float bz = pbBase[i * 3 + 2];
        const float b2 = fmaf(bx, bx, fmaf(by, by, bz * bz));
        sb[i] = make_float4(bx, by, bz, b2);
    }
    __syncthreads();

    float m2x[RROWS], m2y[RROWS], m2z[RROWS], a2[RROWS], mind[RROWS];
    const int n0 = tile * ROWS_PER_BLOCK;
#pragma unroll
    for (int k = 0; k < RROWS; ++k) {
        const int row = n0 + k * TPB + t;
        const float ax = paBase[row * 3 + 0];
        const float ay = paBase[row * 3 + 1];
        const float az = paBase[row * 3 + 2];
        a2[k]  = fmaf(ax, ax, fmaf(ay, ay, az * az));
        m2x[k] = -2.0f * ax;
        m2y[k] = -2.0f * ay;
        m2z[k] = -2.0f * az;
        mind[k] = 3.0e38f;
    }

#pragma unroll 8
    for (int m = 0; m < SLICE; ++m) {
        const float4 b = sb[m];          // one ds_read_b128, broadcast
#pragma unroll
        for (int k = 0; k < RROWS; ++k) {
            float v = fmaf(m2x[k], b.x, b.w);   // b2 - 2ax*bx
            v = fmaf(m2y[k], b.y, v);
            v = fmaf(m2z[k], b.z, v);
            mind[k] = fminf(mind[k], v);        // 4 VALU ops / pair
        }
    }

    const unsigned rowBase = (unsigned)dir * (BATCH * NPTS) + (unsigned)batch * NPTS;
#pragma unroll
    for (int k = 0; k < RROWS; ++k) {
        const int row = n0 + k * TPB + t;
        atomicMin(&minkey[rowBase + row], fkey(a2[k] + mind[k]));
    }
}

// Kernel 2: decode key, sqrt(max(d2,1e-12)), per-block deterministic sums.
__global__ __launch_bounds__(256) void reduce_rows_kernel(
    const unsigned int* __restrict__ minkey, float* __restrict__ blockSums)
{
    const int gid = blockIdx.x * 256 + threadIdx.x;
    const float v = funkey(minkey[gid]);
    float d = sqrtf(fmaxf(v, 1e-12f));
#pragma unroll
    for (int off = 32; off; off >>= 1) d += __shfl_down(d, off);
    __shared__ float wsum[4];
    const int wave = threadIdx.x >> 6, lane = threadIdx.x & 63;
    if (lane == 0) wsum[wave] = d;
    __syncthreads();
    if (threadIdx.x == 0)
        blockSums[blockIdx.x] = (wsum[0] + wsum[1]) + (wsum[2] + wsum[3]);
}

// Kernel 3: final deterministic sum of 256 block sums -> mean.
__global__ __launch_bounds__(256) void final_kernel(
    const float* __restrict__ blockSums, float* __restrict__ out)
{
    float d = blockSums[threadIdx.x];
#pragma unroll
    for (int off = 32; off; off >>= 1) d += __shfl_down(d, off);
    __shared__ float wsum[4];
    const int wave = threadIdx.x >> 6, lane = threadIdx.x & 63;
    if (lane == 0) wsum[wave] = d;
    __syncthreads();
    if (threadIdx.x == 0) {
        const float total = (wsum[0] + wsum[1]) + (wsum[2] + wsum[3]);
        out[0] = total / (float)(BATCH * NPTS);  // both directions share /32768
    }
}

extern "C" void kernel_launch(void* const* d_in, const int* in_sizes, int n_in,
                              void* d_out, int out_size, void* d_ws, size_t ws_size,
                              hipStream_t stream) {
    const float* tpl = (const float*)d_in[0];
    const float* src = (const float*)d_in[1];
    float* out = (float*)d_out;

    unsigned int* minkey = (unsigned int*)d_ws;
    float* blockSums = (float*)d_ws + TOTAL_ROWS;

    // Init keys to 0xFFFFFFFF (max key). Graph-capture safe.
    hipMemsetAsync(d_ws, 0xFF, (size_t)TOTAL_ROWS * sizeof(unsigned int), stream);

    dim3 grid1(TOTAL_ROWS / ROWS_PER_BLOCK, NSLICES);   // (64, 16)
    chamfer_min_kernel<<<grid1, TPB, 0, stream>>>(tpl, src, minkey);

    reduce_rows_kernel<<<TOTAL_ROWS / 256, 256, 0, stream>>>(minkey, blockSums);
    final_kernel<<<1, 256, 0, stream>>>(blockSums, out);
}